// Round 1
// baseline (599.166 us; speedup 1.0000x reference)
//
#include <hip/hip_runtime.h>
#include <cstdint>
#include <cstddef>

#define N_NODES 8192
#define IN_DIM  256
#define OUT_DIM 64
#define HEADS   2
#define FEAT    128           // OUT_DIM*HEADS
#define NTILES  9             // 144 B-cols: 128 feat + 2 denom + 14 pad
#define ACC_STRIDE 132
#define KSPLIT  4             // was 8: halves the accum round-trip (69->35 MB HBM)

typedef __bf16 bf16x8 __attribute__((ext_vector_type(8)));
typedef float  f32x4  __attribute__((ext_vector_type(4)));
typedef int    i32x4  __attribute__((ext_vector_type(4)));
typedef unsigned uu32x4 __attribute__((ext_vector_type(4)));

static __device__ __forceinline__ unsigned short f2bf(float f) {
  unsigned u = __float_as_uint(f);
  u += 0x7FFFu + ((u >> 16) & 1u);     // round-to-nearest-even
  return (unsigned short)(u >> 16);
}

// ---------------------------------------------------------------- k_prep
// Fused: H-tile matmul (registers) + er reduction + exp + bf16 fragment pack.
// 256 blocks; block kb owns source rows j0 = kb*32 .. j0+31, all 128 cols.
// Emits frag[kb][n][lane] (uint4 = 8 bf16, j-octet per lane) — same layout
// k_main consumes: lane l -> col n*16+(l&15), j = (l>>4)*8 + t.
__global__ __launch_bounds__(256) void k_prep(const float* __restrict__ x,
                                              const float* __restrict__ W,
                                              const float* __restrict__ attn_r,
                                              uint4* __restrict__ frag) {
  const int kb = blockIdx.x;                 // 0..255
  const int tid = threadIdx.x;
  const int tx = tid & 15, ty = tid >> 4;    // ty 0..15
  const int j0 = kb * 32;

  __shared__ float xs[32][68];               // [row][k] 8.7 KB
  __shared__ float wl[128][68];              // [col][k] 34.8 KB
  __shared__ unsigned short pk[32][146];     // bf16 pack buffer 9.3 KB

  float acc[2][8] = {};                      // rows ty, ty+16; cols tx+jj*16

  for (int kc = 0; kc < IN_DIM; kc += 64) {
    __syncthreads();
    // stage x-tile: 512 float4 slots, 2 per thread
#pragma unroll
    for (int p = 0; p < 2; p++) {
      const int slot = p*256 + tid;
      const int r = slot >> 4, k4 = slot & 15;
      *(float4*)&xs[r][k4*4] = *(const float4*)(x + (size_t)(j0 + r)*IN_DIM + kc + k4*4);
    }
    // stage W-tile: 2048 float4 slots, 8 per thread
#pragma unroll
    for (int p = 0; p < 8; p++) {
      const int slot = p*256 + tid;
      const int r = slot >> 4, k4 = slot & 15;
      *(float4*)&wl[r][k4*4] = *(const float4*)(W + (size_t)r*IN_DIM + kc + k4*4);
    }
    __syncthreads();
#pragma unroll
    for (int k4 = 0; k4 < 16; k4++) {
      float4 xr[2], wr[8];
#pragma unroll
      for (int i = 0; i < 2; i++) xr[i] = *(const float4*)&xs[ty + i*16][k4*4];
#pragma unroll
      for (int jj = 0; jj < 8; jj++) wr[jj] = *(const float4*)&wl[tx + jj*16][k4*4];
#pragma unroll
      for (int i = 0; i < 2; i++)
#pragma unroll
        for (int jj = 0; jj < 8; jj++)
          acc[i][jj] += xr[i].x*wr[jj].x + xr[i].y*wr[jj].y +
                        xr[i].z*wr[jj].z + xr[i].w*wr[jj].w;
    }
  }

  // er[row][h] = sum_d H[row][h*64+d] * attn_r[h][d]; cols jj<4 -> h0, jj>=4 -> h1
  float ar[8];
#pragma unroll
  for (int jj = 0; jj < 8; jj++)
    ar[jj] = attn_r[((jj >> 2)) * OUT_DIM + ((tx + jj*16) & 63)];
  float e0[2] = {}, e1[2] = {};
#pragma unroll
  for (int i = 0; i < 2; i++) {
#pragma unroll
    for (int jj = 0; jj < 4; jj++) e0[i] += acc[i][jj] * ar[jj];
#pragma unroll
    for (int jj = 4; jj < 8; jj++) e1[i] += acc[i][jj] * ar[jj];
  }
#pragma unroll
  for (int m = 1; m <= 8; m <<= 1) {
#pragma unroll
    for (int i = 0; i < 2; i++) {
      e0[i] += __shfl_xor(e0[i], m);
      e1[i] += __shfl_xor(e1[i], m);
    }
  }
  float w0[2], w1[2];
#pragma unroll
  for (int i = 0; i < 2; i++) { w0[i] = __expf(e0[i]); w1[i] = __expf(e1[i]); }

  // pack: pk[row][col] = bf16(w*H), denom cols 128/129 = bf16(w), 130..143 = 0
#pragma unroll
  for (int i = 0; i < 2; i++) {
    const int row = ty + i*16;
#pragma unroll
    for (int jj = 0; jj < 8; jj++)
      pk[row][tx + jj*16] = f2bf((jj < 4 ? w0[i] : w1[i]) * acc[i][jj]);
    pk[row][128 + tx] = (tx == 0) ? f2bf(w0[i]) : (tx == 1) ? f2bf(w1[i]) : 0;
  }
  __syncthreads();

  // emit 576 uint4 words: word = n*64 + l
#pragma unroll
  for (int t = 0; t < 3; t++) {
    const int wid = t*256 + tid;
    if (wid < 576) {
      const int l = wid & 63, n = wid >> 6;
      const int col = n*16 + (l & 15), jb = (l >> 4) * 8;
      uint4 o;
      o.x = (unsigned)pk[jb+0][col] | ((unsigned)pk[jb+1][col] << 16);
      o.y = (unsigned)pk[jb+2][col] | ((unsigned)pk[jb+3][col] << 16);
      o.z = (unsigned)pk[jb+4][col] | ((unsigned)pk[jb+5][col] << 16);
      o.w = (unsigned)pk[jb+6][col] | ((unsigned)pk[jb+7][col] << 16);
      frag[((size_t)kb*NTILES + n)*64 + l] = o;
    }
  }
}

// ---------------------------------------------------------------- k_main
// accum[ks][8192][132] = adj[:, ks-slice] @ B[ks-slice, 144]  (bf16 MFMA, fp32 acc)
// Barrier-free: no LDS, B fragments read straight from L1/L2, A double-buffered
// in registers. Grid 512 = 128 M-blocks (64 rows) x 4 K-splits. 4 waves/block,
// each wave: one 16-row MFMA strip x 144 cols over K=2048 (64 kk-steps of 32).
// vs KSPLIT=8: same grid/occupancy, same adj coalescing, half the accum traffic,
// acc regs 72->36. Plain stores to per-split slice (no atomics).
__global__ __launch_bounds__(256, 2) void k_main(const int* __restrict__ adj,
                                                 const uint4* __restrict__ fragB,
                                                 float* __restrict__ accum) {
  const int mb = blockIdx.x >> 2;         // 0..127 (64-row tile)
  const int ks = blockIdx.x & 3;          // 0..3   (K-range ks*2048..+2047)
  const int tid = threadIdx.x;
  const int wave = tid >> 6, lane = tid & 63;
  const int m16 = lane & 15, quad = lane >> 4;

  const int row0 = mb*64 + wave*16 + m16;
  const int* a0 = adj + (size_t)row0*N_NODES + ks*2048 + quad*8;
  const uint4* bb = fragB + (size_t)(ks*64)*NTILES*64 + lane;   // kb base = ks*64

  f32x4 acc[NTILES];
#pragma unroll
  for (int n = 0; n < NTILES; n++) acc[n] = (f32x4){0.f, 0.f, 0.f, 0.f};

  i32x4  Abuf[2][2];
  uu32x4 Bbuf[2][NTILES];

  auto loadA = [&](int kk, int buf) {
    const i32x4* p = (const i32x4*)(a0 + kk*32);
    Abuf[buf][0] = __builtin_nontemporal_load(p);
    Abuf[buf][1] = __builtin_nontemporal_load(p + 1);
  };
  auto loadB = [&](int kk, int buf) {
    const uu32x4* b = (const uu32x4*)bb;
#pragma unroll
    for (int t = 0; t < NTILES; t++)
      Bbuf[buf][t] = b[(size_t)(kk*NTILES + t)*64];
  };
  auto conv = [&](const i32x4* A) -> bf16x8 {
    const int* ai = (const int*)A;
    unsigned u0 = (ai[0] ? 0x3F80u : 0u) | (ai[1] ? 0x3F800000u : 0u);
    unsigned u1 = (ai[2] ? 0x3F80u : 0u) | (ai[3] ? 0x3F800000u : 0u);
    unsigned u2 = (ai[4] ? 0x3F80u : 0u) | (ai[5] ? 0x3F800000u : 0u);
    unsigned u3 = (ai[6] ? 0x3F80u : 0u) | (ai[7] ? 0x3F800000u : 0u);
    uu32x4 u = {u0, u1, u2, u3};
    return __builtin_bit_cast(bf16x8, u);
  };
  auto compute = [&](int buf) {
    bf16x8 af = conv(&Abuf[buf][0]);
#pragma unroll
    for (int n = 0; n < NTILES; n++) {
      bf16x8 bfr = __builtin_bit_cast(bf16x8, Bbuf[buf][n]);
      acc[n] = __builtin_amdgcn_mfma_f32_16x16x32_bf16(af, bfr, acc[n], 0, 0, 0);
    }
  };

  loadA(0, 0); loadB(0, 0);
  for (int kk = 0; kk < 64; kk += 2) {
    loadA(kk + 1, 1); loadB(kk + 1, 1);
    compute(0);
    const int k2 = (kk + 2 < 64) ? kk + 2 : 63;   // clamp: redundant safe reload at tail
    loadA(k2, 0); loadB(k2, 0);
    compute(1);
  }

  // epilogue: C/D layout col=lane&15, row=quad*4+reg. Plain stores.
  const int rb0 = mb*64 + wave*16 + quad*4;
  float* op = accum + (size_t)ks*N_NODES*ACC_STRIDE;
#pragma unroll
  for (int n = 0; n < NTILES; n++) {
    if (n == 8 && m16 >= HEADS) continue;  // cols 130..143 are padding
#pragma unroll
    for (int r = 0; r < 4; r++)
      op[(size_t)(rb0 + r)*ACC_STRIDE + n*16 + m16] = acc[n][r];
  }
}

// ---------------------------------------------------------------- k_div
// out[i][c] = (sum_ks num) / (sum_ks den)
__global__ void k_div(const float* __restrict__ acc, float* __restrict__ out) {
  const int i = blockIdx.x, c = threadIdx.x;   // 8192 x 128
  const int h = c >> 6;
  float num = 0.f, den = 0.f;
#pragma unroll
  for (int s = 0; s < KSPLIT; s++) {
    const float* p = acc + ((size_t)s*N_NODES + i)*ACC_STRIDE;
    num += p[c];
    den += p[FEAT + h];
  }
  out[(size_t)i*FEAT + c] = num / den;
}

// ---------------------------------------------------------------- launch
extern "C" void kernel_launch(void* const* d_in, const int* in_sizes, int n_in,
                              void* d_out, int out_size, void* d_ws, size_t ws_size,
                              hipStream_t stream) {
  const float* x      = (const float*)d_in[0];
  const int*   adj    = (const int*)  d_in[1];
  const float* W      = (const float*)d_in[2];
  // d_in[3] = attn_l: cancels in softmax over j — unused.
  const float* attn_r = (const float*)d_in[4];

  char* ws = (char*)d_ws;
  uint4* frag = (uint4*)(ws + 0);              // 2.36 MB
  float* acc  = (float*)(ws + 4194304);        // 4 x 4.33 MB
  float* out  = (float*)d_out;

  hipLaunchKernelGGL(k_prep, dim3(256),  dim3(256), 0, stream, x, W, attn_r, frag);
  hipLaunchKernelGGL(k_main, dim3(512),  dim3(256), 0, stream, adj, frag, acc);
  hipLaunchKernelGGL(k_div,  dim3(8192), dim3(128), 0, stream, acc, out);
}

// Round 2
// 430.966 us; speedup vs baseline: 1.3903x; 1.3903x over previous
//
#include <hip/hip_runtime.h>
#include <cstdint>
#include <cstddef>

#define N_NODES 8192
#define IN_DIM  256
#define OUT_DIM 64
#define HEADS   2
#define FEAT    128           // OUT_DIM*HEADS
#define NTILES  9             // 144 B-cols: 128 feat + 2 denom + 14 pad
#define ACC_STRIDE 132
#define KSPLIT  8

typedef __bf16 bf16x8 __attribute__((ext_vector_type(8)));
typedef float  f32x4  __attribute__((ext_vector_type(4)));
typedef int    i32x4  __attribute__((ext_vector_type(4)));
typedef unsigned uu32x4 __attribute__((ext_vector_type(4)));

static __device__ __forceinline__ unsigned short f2bf(float f) {
  unsigned u = __float_as_uint(f);
  u += 0x7FFFu + ((u >> 16) & 1u);     // round-to-nearest-even
  return (unsigned short)(u >> 16);
}

// ---------------------------------------------------------------- k_prep
// Fused: H-tile matmul (registers) + er reduction + exp + bf16 fragment pack.
// 256 blocks; block kb owns source rows j0 = kb*32 .. j0+31, all 128 cols.
// Emits frag[kb][n][lane] (uint4 = 8 bf16, j-octet per lane) — same layout
// k_main consumes: lane l -> col n*16+(l&15), j = (l>>4)*8 + t.
__global__ __launch_bounds__(256) void k_prep(const float* __restrict__ x,
                                              const float* __restrict__ W,
                                              const float* __restrict__ attn_r,
                                              uint4* __restrict__ frag) {
  const int kb = blockIdx.x;                 // 0..255
  const int tid = threadIdx.x;
  const int tx = tid & 15, ty = tid >> 4;    // ty 0..15
  const int j0 = kb * 32;

  __shared__ float xs[32][68];               // [row][k] 8.7 KB
  __shared__ float wl[128][68];              // [col][k] 34.8 KB
  __shared__ unsigned short pk[32][146];     // bf16 pack buffer 9.3 KB

  float acc[2][8] = {};                      // rows ty, ty+16; cols tx+jj*16

  for (int kc = 0; kc < IN_DIM; kc += 64) {
    __syncthreads();
    // stage x-tile: 512 float4 slots, 2 per thread
#pragma unroll
    for (int p = 0; p < 2; p++) {
      const int slot = p*256 + tid;
      const int r = slot >> 4, k4 = slot & 15;
      *(float4*)&xs[r][k4*4] = *(const float4*)(x + (size_t)(j0 + r)*IN_DIM + kc + k4*4);
    }
    // stage W-tile: 2048 float4 slots, 8 per thread
#pragma unroll
    for (int p = 0; p < 8; p++) {
      const int slot = p*256 + tid;
      const int r = slot >> 4, k4 = slot & 15;
      *(float4*)&wl[r][k4*4] = *(const float4*)(W + (size_t)r*IN_DIM + kc + k4*4);
    }
    __syncthreads();
#pragma unroll
    for (int k4 = 0; k4 < 16; k4++) {
      float4 xr[2], wr[8];
#pragma unroll
      for (int i = 0; i < 2; i++) xr[i] = *(const float4*)&xs[ty + i*16][k4*4];
#pragma unroll
      for (int jj = 0; jj < 8; jj++) wr[jj] = *(const float4*)&wl[tx + jj*16][k4*4];
#pragma unroll
      for (int i = 0; i < 2; i++)
#pragma unroll
        for (int jj = 0; jj < 8; jj++)
          acc[i][jj] += xr[i].x*wr[jj].x + xr[i].y*wr[jj].y +
                        xr[i].z*wr[jj].z + xr[i].w*wr[jj].w;
    }
  }

  // er[row][h] = sum_d H[row][h*64+d] * attn_r[h][d]; cols jj<4 -> h0, jj>=4 -> h1
  float ar[8];
#pragma unroll
  for (int jj = 0; jj < 8; jj++)
    ar[jj] = attn_r[((jj >> 2)) * OUT_DIM + ((tx + jj*16) & 63)];
  float e0[2] = {}, e1[2] = {};
#pragma unroll
  for (int i = 0; i < 2; i++) {
#pragma unroll
    for (int jj = 0; jj < 4; jj++) e0[i] += acc[i][jj] * ar[jj];
#pragma unroll
    for (int jj = 4; jj < 8; jj++) e1[i] += acc[i][jj] * ar[jj];
  }
#pragma unroll
  for (int m = 1; m <= 8; m <<= 1) {
#pragma unroll
    for (int i = 0; i < 2; i++) {
      e0[i] += __shfl_xor(e0[i], m);
      e1[i] += __shfl_xor(e1[i], m);
    }
  }
  float w0[2], w1[2];
#pragma unroll
  for (int i = 0; i < 2; i++) { w0[i] = __expf(e0[i]); w1[i] = __expf(e1[i]); }

  // pack: pk[row][col] = bf16(w*H), denom cols 128/129 = bf16(w), 130..143 = 0
#pragma unroll
  for (int i = 0; i < 2; i++) {
    const int row = ty + i*16;
#pragma unroll
    for (int jj = 0; jj < 8; jj++)
      pk[row][tx + jj*16] = f2bf((jj < 4 ? w0[i] : w1[i]) * acc[i][jj]);
    pk[row][128 + tx] = (tx == 0) ? f2bf(w0[i]) : (tx == 1) ? f2bf(w1[i]) : 0;
  }
  __syncthreads();

  // emit 576 uint4 words: word = n*64 + l
#pragma unroll
  for (int t = 0; t < 3; t++) {
    const int wid = t*256 + tid;
    if (wid < 576) {
      const int l = wid & 63, n = wid >> 6;
      const int col = n*16 + (l & 15), jb = (l >> 4) * 8;
      uint4 o;
      o.x = (unsigned)pk[jb+0][col] | ((unsigned)pk[jb+1][col] << 16);
      o.y = (unsigned)pk[jb+2][col] | ((unsigned)pk[jb+3][col] << 16);
      o.z = (unsigned)pk[jb+4][col] | ((unsigned)pk[jb+5][col] << 16);
      o.w = (unsigned)pk[jb+6][col] | ((unsigned)pk[jb+7][col] << 16);
      frag[((size_t)kb*NTILES + n)*64 + l] = o;
    }
  }
}

// ---------------------------------------------------------------- k_main
// accum[ks][8192][132] = adj[:, ks-slice] @ B[ks-slice, 144]  (bf16 MFMA, fp32 acc)
// m97-style LDS pipeline: adj tile (128 rows x 32 cols int) staged via
// global_load_lds (width 16, zero VGPR in-flight cost), double-buffered LDS,
// one barrier per K-step. Per-lane global addresses are pre-swizzled
// (byte ^= (row&7)<<4) so the linear LDS write lands XOR-swizzled and the
// stride-128B ds_read_b128 is a free 2-way bank conflict instead of 16-way.
// Grid 512 = 64 M-blocks (128 rows) x 8 K-splits; 4 waves/block, 32 rows/wave.
// B fragments single-buffered in 9 constant-indexed regs (L2-resident).
__global__ __launch_bounds__(256, 2) void k_main(const int* __restrict__ adj,
                                                 const uint4* __restrict__ fragB,
                                                 float* __restrict__ accum) {
  const int mb = blockIdx.x >> 3;         // 0..63
  const int ks = blockIdx.x & 7;          // 0..7
  const int tid = threadIdx.x;
  const int wave = tid >> 6, lane = tid & 63;
  const int m16 = lane & 15, quad = lane >> 4;

  __shared__ int tile[2][4096];           // 2 x 16 KB adj tile, [row][32 ints] swizzled

  // per-lane staging geometry: lane l covers row (chunk*8 + l>>3),
  // 16B slot ((l&7) ^ (l>>3)) of the 128B row  -> LDS write is linear in l.
  const int lr = lane >> 3;                       // 0..7 row within chunk
  const int lc = ((lane & 7) ^ lr) << 2;          // int offset within row (swizzled src)
  const int kb0 = ks * 1024;
  const int* gbase = adj + (size_t)(mb*128)*N_NODES + kb0 + (size_t)lr*N_NODES + lc;

  auto stage = [&](int buf, int kk) {
#pragma unroll
    for (int i = 0; i < 4; ++i) {
      const int c = wave*4 + i;                   // chunk 0..15 (8 rows each)
      const int* g = gbase + (size_t)(c*8)*N_NODES + kk*32;
      __builtin_amdgcn_global_load_lds(
        (const __attribute__((address_space(1))) void*)g,
        (__attribute__((address_space(3))) void*)&tile[buf][c*256],
        16, 0, 0);
    }
  };

  // A fragment read geometry (per wave strips: rows wave*32+m16, +16)
  const int r0 = wave*32 + m16;
  const int swz = (r0 & 7) << 4;                  // (r&7) identical for r0, r0+16
  const int a0off = r0*128 + ((quad*32) ^ swz);   // byte offset into tile
  const uu32x4* bb = (const uu32x4*)fragB + lane;

  f32x4 acc0[NTILES], acc1[NTILES];
#pragma unroll
  for (int n = 0; n < NTILES; n++) {
    acc0[n] = (f32x4){0.f, 0.f, 0.f, 0.f};
    acc1[n] = (f32x4){0.f, 0.f, 0.f, 0.f};
  }

  auto conv8 = [&](i32x4 lo, i32x4 hi) -> bf16x8 {
    unsigned u0 = (lo[0] ? 0x3F80u : 0u) | (lo[1] ? 0x3F800000u : 0u);
    unsigned u1 = (lo[2] ? 0x3F80u : 0u) | (lo[3] ? 0x3F800000u : 0u);
    unsigned u2 = (hi[0] ? 0x3F80u : 0u) | (hi[1] ? 0x3F800000u : 0u);
    unsigned u3 = (hi[2] ? 0x3F80u : 0u) | (hi[3] ? 0x3F800000u : 0u);
    uu32x4 u = {u0, u1, u2, u3};
    return __builtin_bit_cast(bf16x8, u);
  };

  stage(0, 0);
  __syncthreads();                                // tile 0 resident

  for (int kk = 0; kk < 32; ++kk) {
    const int cur = kk & 1;
    if (kk + 1 < 32) stage(cur ^ 1, kk + 1);      // issue next tile (in flight across step)

    // B fragments for this k-block (kb = ks*32 + kk), 9 x 16B from L2
    uu32x4 bv[NTILES];
    {
      const uu32x4* bp = bb + (size_t)(ks*32 + kk)*NTILES*64;
#pragma unroll
      for (int t = 0; t < NTILES; t++) bv[t] = bp[t*64];
    }

    // A fragments from LDS (swizzled): 4 x ds_read_b128
    const char* tb = (const char*)&tile[cur][0];
    i32x4 x00 = *(const i32x4*)(tb + a0off);
    i32x4 x01 = *(const i32x4*)(tb + (a0off ^ 16));
    i32x4 x10 = *(const i32x4*)(tb + a0off + 2048);
    i32x4 x11 = *(const i32x4*)(tb + (a0off ^ 16) + 2048);

    bf16x8 af0 = conv8(x00, x01);
    bf16x8 af1 = conv8(x10, x11);
#pragma unroll
    for (int n = 0; n < NTILES; n++) {
      bf16x8 bfr = __builtin_bit_cast(bf16x8, bv[n]);
      acc0[n] = __builtin_amdgcn_mfma_f32_16x16x32_bf16(af0, bfr, acc0[n], 0, 0, 0);
    }
#pragma unroll
    for (int n = 0; n < NTILES; n++) {
      bf16x8 bfr = __builtin_bit_cast(bf16x8, bv[n]);
      acc1[n] = __builtin_amdgcn_mfma_f32_16x16x32_bf16(af1, bfr, acc1[n], 0, 0, 0);
    }

    __syncthreads();                              // drains stage loads; tile cur^1 ready
  }

  // epilogue: C/D layout col=lane&15, row=quad*4+reg. Plain stores.
  const int rb0 = mb*128 + wave*32 + quad*4;
  float* op = accum + (size_t)ks*N_NODES*ACC_STRIDE;
#pragma unroll
  for (int n = 0; n < NTILES; n++) {
    if (n == 8 && m16 >= HEADS) continue;  // cols 130..143 are padding
#pragma unroll
    for (int r = 0; r < 4; r++) {
      op[(size_t)(rb0 + r)*ACC_STRIDE + n*16 + m16]      = acc0[n][r];
      op[(size_t)(rb0 + 16 + r)*ACC_STRIDE + n*16 + m16] = acc1[n][r];
    }
  }
}

// ---------------------------------------------------------------- k_div
// out[i][c] = (sum_ks num) / (sum_ks den)
__global__ void k_div(const float* __restrict__ acc, float* __restrict__ out) {
  const int i = blockIdx.x, c = threadIdx.x;   // 8192 x 128
  const int h = c >> 6;
  float num = 0.f, den = 0.f;
#pragma unroll
  for (int s = 0; s < KSPLIT; s++) {
    const float* p = acc + ((size_t)s*N_NODES + i)*ACC_STRIDE;
    num += p[c];
    den += p[FEAT + h];
  }
  out[(size_t)i*FEAT + c] = num / den;
}

// ---------------------------------------------------------------- launch
extern "C" void kernel_launch(void* const* d_in, const int* in_sizes, int n_in,
                              void* d_out, int out_size, void* d_ws, size_t ws_size,
                              hipStream_t stream) {
  const float* x      = (const float*)d_in[0];
  const int*   adj    = (const int*)  d_in[1];
  const float* W      = (const float*)d_in[2];
  // d_in[3] = attn_l: cancels in softmax over j — unused.
  const float* attn_r = (const float*)d_in[4];

  char* ws = (char*)d_ws;
  uint4* frag = (uint4*)(ws + 0);              // 2.36 MB
  float* acc  = (float*)(ws + 4194304);        // 8 x 4.33 MB
  float* out  = (float*)d_out;

  hipLaunchKernelGGL(k_prep, dim3(256),  dim3(256), 0, stream, x, W, attn_r, frag);
  hipLaunchKernelGGL(k_main, dim3(512),  dim3(256), 0, stream, adj, frag, acc);
  hipLaunchKernelGGL(k_div,  dim3(8192), dim3(128), 0, stream, acc, out);
}

// Round 3
// 429.065 us; speedup vs baseline: 1.3964x; 1.0044x over previous
//
#include <hip/hip_runtime.h>
#include <cstdint>
#include <cstddef>

#define N_NODES 8192
#define IN_DIM  256
#define OUT_DIM 64
#define HEADS   2
#define FEAT    128           // OUT_DIM*HEADS
#define NTILES  9             // 144 B-cols: 128 feat + 2 denom + 14 pad
#define ACC_STRIDE 132
#define KSPLIT  8

typedef __bf16 bf16x8 __attribute__((ext_vector_type(8)));
typedef float  f32x4  __attribute__((ext_vector_type(4)));
typedef int    i32x4  __attribute__((ext_vector_type(4)));
typedef unsigned uu32x4 __attribute__((ext_vector_type(4)));

static __device__ __forceinline__ unsigned short f2bf(float f) {
  unsigned u = __float_as_uint(f);
  u += 0x7FFFu + ((u >> 16) & 1u);     // round-to-nearest-even
  return (unsigned short)(u >> 16);
}

// ---------------------------------------------------------------- k_prep
// Fused: H-tile matmul (registers) + er reduction + exp + bf16 fragment pack.
// 256 blocks; block kb owns source rows j0 = kb*32 .. j0+31, all 128 cols.
__global__ __launch_bounds__(256) void k_prep(const float* __restrict__ x,
                                              const float* __restrict__ W,
                                              const float* __restrict__ attn_r,
                                              uint4* __restrict__ frag) {
  const int kb = blockIdx.x;                 // 0..255
  const int tid = threadIdx.x;
  const int tx = tid & 15, ty = tid >> 4;    // ty 0..15
  const int j0 = kb * 32;

  __shared__ float xs[32][68];               // [row][k] 8.7 KB
  __shared__ float wl[128][68];              // [col][k] 34.8 KB
  __shared__ unsigned short pk[32][146];     // bf16 pack buffer 9.3 KB

  float acc[2][8] = {};                      // rows ty, ty+16; cols tx+jj*16

  for (int kc = 0; kc < IN_DIM; kc += 64) {
    __syncthreads();
    // stage x-tile: 512 float4 slots, 2 per thread
#pragma unroll
    for (int p = 0; p < 2; p++) {
      const int slot = p*256 + tid;
      const int r = slot >> 4, k4 = slot & 15;
      *(float4*)&xs[r][k4*4] = *(const float4*)(x + (size_t)(j0 + r)*IN_DIM + kc + k4*4);
    }
    // stage W-tile: 2048 float4 slots, 8 per thread
#pragma unroll
    for (int p = 0; p < 8; p++) {
      const int slot = p*256 + tid;
      const int r = slot >> 4, k4 = slot & 15;
      *(float4*)&wl[r][k4*4] = *(const float4*)(W + (size_t)r*IN_DIM + kc + k4*4);
    }
    __syncthreads();
#pragma unroll
    for (int k4 = 0; k4 < 16; k4++) {
      float4 xr[2], wr[8];
#pragma unroll
      for (int i = 0; i < 2; i++) xr[i] = *(const float4*)&xs[ty + i*16][k4*4];
#pragma unroll
      for (int jj = 0; jj < 8; jj++) wr[jj] = *(const float4*)&wl[tx + jj*16][k4*4];
#pragma unroll
      for (int i = 0; i < 2; i++)
#pragma unroll
        for (int jj = 0; jj < 8; jj++)
          acc[i][jj] += xr[i].x*wr[jj].x + xr[i].y*wr[jj].y +
                        xr[i].z*wr[jj].z + xr[i].w*wr[jj].w;
    }
  }

  // er[row][h] = sum_d H[row][h*64+d] * attn_r[h][d]; cols jj<4 -> h0, jj>=4 -> h1
  float ar[8];
#pragma unroll
  for (int jj = 0; jj < 8; jj++)
    ar[jj] = attn_r[((jj >> 2)) * OUT_DIM + ((tx + jj*16) & 63)];
  float e0[2] = {}, e1[2] = {};
#pragma unroll
  for (int i = 0; i < 2; i++) {
#pragma unroll
    for (int jj = 0; jj < 4; jj++) e0[i] += acc[i][jj] * ar[jj];
#pragma unroll
    for (int jj = 4; jj < 8; jj++) e1[i] += acc[i][jj] * ar[jj];
  }
#pragma unroll
  for (int m = 1; m <= 8; m <<= 1) {
#pragma unroll
    for (int i = 0; i < 2; i++) {
      e0[i] += __shfl_xor(e0[i], m);
      e1[i] += __shfl_xor(e1[i], m);
    }
  }
  float w0[2], w1[2];
#pragma unroll
  for (int i = 0; i < 2; i++) { w0[i] = __expf(e0[i]); w1[i] = __expf(e1[i]); }

  // pack: pk[row][col] = bf16(w*H), denom cols 128/129 = bf16(w), 130..143 = 0
#pragma unroll
  for (int i = 0; i < 2; i++) {
    const int row = ty + i*16;
#pragma unroll
    for (int jj = 0; jj < 8; jj++)
      pk[row][tx + jj*16] = f2bf((jj < 4 ? w0[i] : w1[i]) * acc[i][jj]);
    pk[row][128 + tx] = (tx == 0) ? f2bf(w0[i]) : (tx == 1) ? f2bf(w1[i]) : 0;
  }
  __syncthreads();

  // emit 576 uint4 words: word = n*64 + l
#pragma unroll
  for (int t = 0; t < 3; t++) {
    const int wid = t*256 + tid;
    if (wid < 576) {
      const int l = wid & 63, n = wid >> 6;
      const int col = n*16 + (l & 15), jb = (l >> 4) * 8;
      uint4 o;
      o.x = (unsigned)pk[jb+0][col] | ((unsigned)pk[jb+1][col] << 16);
      o.y = (unsigned)pk[jb+2][col] | ((unsigned)pk[jb+3][col] << 16);
      o.z = (unsigned)pk[jb+4][col] | ((unsigned)pk[jb+5][col] << 16);
      o.w = (unsigned)pk[jb+6][col] | ((unsigned)pk[jb+7][col] << 16);
      frag[((size_t)kb*NTILES + n)*64 + l] = o;
    }
  }
}

// ---------------------------------------------------------------- k_main
// accum[ks][8192][132] = adj[:, ks-slice] @ B[ks-slice, 144]  (bf16 MFMA, fp32 acc)
// Counted-vmcnt pipeline (T3/T4): 4 LDS tile buffers (64 KB), stage issued
// 2 steps ahead via global_load_lds; B fragments register-double-buffered,
// loaded 1 step ahead. Raw s_barrier + asm s_waitcnt vmcnt(13) per step —
// never drains to 0, so ~13 KB/wave (100 KB/CU) stays in flight across
// barriers. Invariant at each step's end-wait: the 13 newest VMEM ops are
// this step's issues (4 stage + 9 B), so vmcnt(13) => stage(k+1) retired
// for every wave => tile[(k+1)&3] fully resident after the barrier.
// Per-lane global addresses pre-swizzled (byte ^= (row&7)<<4) so the linear
// LDS write lands XOR-swizzled and stride-128B ds_read_b128 is conflict-light.
// Grid 512 = 64 M-blocks (128 rows) x 8 K-splits; 4 waves/block, 32 rows/wave.
__global__ __launch_bounds__(256, 2) void k_main(const int* __restrict__ adj,
                                                 const uint4* __restrict__ fragB,
                                                 float* __restrict__ accum) {
  const int mb = blockIdx.x >> 3;         // 0..63
  const int ks = blockIdx.x & 7;          // 0..7
  const int tid = threadIdx.x;
  const int wave = tid >> 6, lane = tid & 63;
  const int m16 = lane & 15, quad = lane >> 4;

  __shared__ int tile[4][4096];           // 4 x 16 KB adj tiles, swizzled rows

  // staging geometry: lane l covers row (chunk*8 + l>>3),
  // 16B slot ((l&7) ^ (l>>3)) of the 128B row -> LDS write linear in l.
  const int lr = lane >> 3;
  const int lc = ((lane & 7) ^ lr) << 2;
  const int* gbase = adj + (size_t)(mb*128)*N_NODES + ks*1024 + (size_t)lr*N_NODES + lc;

  auto stage = [&](int buf, int kk) {
#pragma unroll
    for (int i = 0; i < 4; ++i) {
      const int c = wave*4 + i;                   // chunk 0..15 (8 rows each)
      const int* g = gbase + (size_t)(c*8)*N_NODES + kk*32;
      __builtin_amdgcn_global_load_lds(
        (const __attribute__((address_space(1))) void*)g,
        (__attribute__((address_space(3))) void*)&tile[buf][c*256],
        16, 0, 0);
    }
  };

  // A fragment read geometry (wave strips: rows wave*32+m16, +16)
  const int r0 = wave*32 + m16;
  const int swz = (r0 & 7) << 4;                  // same for r0 and r0+16
  const int a0off = r0*128 + ((quad*32) ^ swz);
  const uu32x4* bb = (const uu32x4*)fragB + (size_t)(ks*32)*NTILES*64 + lane;

  f32x4 acc0[NTILES], acc1[NTILES];
#pragma unroll
  for (int n = 0; n < NTILES; n++) {
    acc0[n] = (f32x4){0.f, 0.f, 0.f, 0.f};
    acc1[n] = (f32x4){0.f, 0.f, 0.f, 0.f};
  }

  uu32x4 bvA[NTILES], bvB[NTILES];

  auto loadB = [&](int kk, uu32x4* bv) {
#pragma unroll
    for (int t = 0; t < NTILES; t++)
      bv[t] = bb[(size_t)kk*NTILES*64 + (size_t)t*64];
  };
  auto conv8 = [&](i32x4 lo, i32x4 hi) -> bf16x8 {
    unsigned u0 = (lo[0] ? 0x3F80u : 0u) | (lo[1] ? 0x3F800000u : 0u);
    unsigned u1 = (lo[2] ? 0x3F80u : 0u) | (lo[3] ? 0x3F800000u : 0u);
    unsigned u2 = (hi[0] ? 0x3F80u : 0u) | (hi[1] ? 0x3F800000u : 0u);
    unsigned u3 = (hi[2] ? 0x3F80u : 0u) | (hi[3] ? 0x3F800000u : 0u);
    uu32x4 u = {u0, u1, u2, u3};
    return __builtin_bit_cast(bf16x8, u);
  };
  auto substep = [&](int buf, const uu32x4* bv) {
    const char* tb = (const char*)&tile[0][0] + buf*16384;
    i32x4 x00 = *(const i32x4*)(tb + a0off);
    i32x4 x01 = *(const i32x4*)(tb + (a0off ^ 16));
    i32x4 x10 = *(const i32x4*)(tb + a0off + 2048);
    i32x4 x11 = *(const i32x4*)(tb + (a0off ^ 16) + 2048);
    bf16x8 af0 = conv8(x00, x01);
    bf16x8 af1 = conv8(x10, x11);
#pragma unroll
    for (int n = 0; n < NTILES; n++) {
      bf16x8 bfr = __builtin_bit_cast(bf16x8, bv[n]);
      acc0[n] = __builtin_amdgcn_mfma_f32_16x16x32_bf16(af0, bfr, acc0[n], 0, 0, 0);
    }
#pragma unroll
    for (int n = 0; n < NTILES; n++) {
      bf16x8 bfr = __builtin_bit_cast(bf16x8, bv[n]);
      acc1[n] = __builtin_amdgcn_mfma_f32_16x16x32_bf16(af1, bfr, acc1[n], 0, 0, 0);
    }
  };

  // prologue: tiles 0,1 in flight, B(0) in flight
  stage(0, 0);
  stage(1, 1);
  loadB(0, bvA);
  asm volatile("s_waitcnt vmcnt(13)" ::: "memory");   // tile0 retired (13 = stage1+B0)
  __builtin_amdgcn_s_barrier();

  for (int k = 0; k < 32; k += 4) {
#pragma unroll
    for (int j = 0; j < 4; ++j) {
      const int kk = k + j;                 // j literal after unroll; kk&1 == j&1
      if (kk + 2 < 32) stage((kk + 2) & 3, kk + 2);
      if (kk + 1 < 32) loadB(kk + 1, (j & 1) ? bvA : bvB);
      substep(kk & 3, (j & 1) ? bvB : bvA);
      // retire everything except this step's issues (<=4 stage + <=9 B):
      asm volatile("s_waitcnt vmcnt(13)" ::: "memory");
      __builtin_amdgcn_s_barrier();
    }
  }

  // epilogue: C/D layout col=lane&15, row=quad*4+reg. Plain stores.
  const int rb0 = mb*128 + wave*32 + quad*4;
  float* op = accum + (size_t)ks*N_NODES*ACC_STRIDE;
#pragma unroll
  for (int n = 0; n < NTILES; n++) {
    if (n == 8 && m16 >= HEADS) continue;  // cols 130..143 are padding
#pragma unroll
    for (int r = 0; r < 4; r++) {
      op[(size_t)(rb0 + r)*ACC_STRIDE + n*16 + m16]      = acc0[n][r];
      op[(size_t)(rb0 + 16 + r)*ACC_STRIDE + n*16 + m16] = acc1[n][r];
    }
  }
}

// ---------------------------------------------------------------- k_div
// out[i][c] = (sum_ks num) / (sum_ks den); vectorized f32x4, 8 rows/block.
__global__ void k_div(const float* __restrict__ acc, float* __restrict__ out) {
  const int tid = threadIdx.x;
  const int r = tid >> 5, c4 = (tid & 31) << 2;   // 8 rows x 32 lanes x float4
  const int i = blockIdx.x * 8 + r;
  const int h = c4 >> 6;
  f32x4 num = (f32x4){0.f, 0.f, 0.f, 0.f};
  float den = 0.f;
#pragma unroll
  for (int s = 0; s < KSPLIT; s++) {
    const float* p = acc + ((size_t)s*N_NODES + i)*ACC_STRIDE;
    num += *(const f32x4*)(p + c4);
    den += p[FEAT + h];
  }
  f32x4 o = num / (f32x4){den, den, den, den};
  *(f32x4*)(out + (size_t)i*FEAT + c4) = o;
}

// ---------------------------------------------------------------- launch
extern "C" void kernel_launch(void* const* d_in, const int* in_sizes, int n_in,
                              void* d_out, int out_size, void* d_ws, size_t ws_size,
                              hipStream_t stream) {
  const float* x      = (const float*)d_in[0];
  const int*   adj    = (const int*)  d_in[1];
  const float* W      = (const float*)d_in[2];
  // d_in[3] = attn_l: cancels in softmax over j — unused.
  const float* attn_r = (const float*)d_in[4];

  char* ws = (char*)d_ws;
  uint4* frag = (uint4*)(ws + 0);              // 2.36 MB
  float* acc  = (float*)(ws + 4194304);        // 8 x 4.33 MB
  float* out  = (float*)d_out;

  hipLaunchKernelGGL(k_prep, dim3(256),  dim3(256), 0, stream, x, W, attn_r, frag);
  hipLaunchKernelGGL(k_main, dim3(512),  dim3(256), 0, stream, adj, frag, acc);
  hipLaunchKernelGGL(k_div,  dim3(1024), dim3(256), 0, stream, acc, out);
}

// Round 4
// 419.591 us; speedup vs baseline: 1.4280x; 1.0226x over previous
//
#include <hip/hip_runtime.h>
#include <cstdint>
#include <cstddef>

#define N_NODES 8192
#define IN_DIM  256
#define OUT_DIM 64
#define HEADS   2
#define FEAT    128           // OUT_DIM*HEADS
#define NTILES  9             // 144 B-cols: 128 feat + 2 denom + 14 pad
#define ACC_STRIDE 132
#define KSPLIT  8

typedef __bf16 bf16x8 __attribute__((ext_vector_type(8)));
typedef float  f32x4  __attribute__((ext_vector_type(4)));
typedef int    i32x4  __attribute__((ext_vector_type(4)));
typedef unsigned uu32x4 __attribute__((ext_vector_type(4)));

static __device__ __forceinline__ unsigned short f2bf(float f) {
  unsigned u = __float_as_uint(f);
  u += 0x7FFFu + ((u >> 16) & 1u);     // round-to-nearest-even
  return (unsigned short)(u >> 16);
}

// ---------------------------------------------------------------- k_prep
// Fused: H-tile matmul (registers) + er reduction + exp + bf16 fragment pack.
// 256 blocks; block kb owns source rows j0 = kb*32 .. j0+31, all 128 cols.
__global__ __launch_bounds__(256) void k_prep(const float* __restrict__ x,
                                              const float* __restrict__ W,
                                              const float* __restrict__ attn_r,
                                              uint4* __restrict__ frag) {
  const int kb = blockIdx.x;                 // 0..255
  const int tid = threadIdx.x;
  const int tx = tid & 15, ty = tid >> 4;    // ty 0..15
  const int j0 = kb * 32;

  __shared__ float xs[32][68];               // [row][k] 8.7 KB
  __shared__ float wl[128][68];              // [col][k] 34.8 KB
  __shared__ unsigned short pk[32][146];     // bf16 pack buffer 9.3 KB

  float acc[2][8] = {};                      // rows ty, ty+16; cols tx+jj*16

  for (int kc = 0; kc < IN_DIM; kc += 64) {
    __syncthreads();
    // stage x-tile: 512 float4 slots, 2 per thread
#pragma unroll
    for (int p = 0; p < 2; p++) {
      const int slot = p*256 + tid;
      const int r = slot >> 4, k4 = slot & 15;
      *(float4*)&xs[r][k4*4] = *(const float4*)(x + (size_t)(j0 + r)*IN_DIM + kc + k4*4);
    }
    // stage W-tile: 2048 float4 slots, 8 per thread
#pragma unroll
    for (int p = 0; p < 8; p++) {
      const int slot = p*256 + tid;
      const int r = slot >> 4, k4 = slot & 15;
      *(float4*)&wl[r][k4*4] = *(const float4*)(W + (size_t)r*IN_DIM + kc + k4*4);
    }
    __syncthreads();
#pragma unroll
    for (int k4 = 0; k4 < 16; k4++) {
      float4 xr[2], wr[8];
#pragma unroll
      for (int i = 0; i < 2; i++) xr[i] = *(const float4*)&xs[ty + i*16][k4*4];
#pragma unroll
      for (int jj = 0; jj < 8; jj++) wr[jj] = *(const float4*)&wl[tx + jj*16][k4*4];
#pragma unroll
      for (int i = 0; i < 2; i++)
#pragma unroll
        for (int jj = 0; jj < 8; jj++)
          acc[i][jj] += xr[i].x*wr[jj].x + xr[i].y*wr[jj].y +
                        xr[i].z*wr[jj].z + xr[i].w*wr[jj].w;
    }
  }

  // er[row][h] = sum_d H[row][h*64+d] * attn_r[h][d]; cols jj<4 -> h0, jj>=4 -> h1
  float ar[8];
#pragma unroll
  for (int jj = 0; jj < 8; jj++)
    ar[jj] = attn_r[((jj >> 2)) * OUT_DIM + ((tx + jj*16) & 63)];
  float e0[2] = {}, e1[2] = {};
#pragma unroll
  for (int i = 0; i < 2; i++) {
#pragma unroll
    for (int jj = 0; jj < 4; jj++) e0[i] += acc[i][jj] * ar[jj];
#pragma unroll
    for (int jj = 4; jj < 8; jj++) e1[i] += acc[i][jj] * ar[jj];
  }
#pragma unroll
  for (int m = 1; m <= 8; m <<= 1) {
#pragma unroll
    for (int i = 0; i < 2; i++) {
      e0[i] += __shfl_xor(e0[i], m);
      e1[i] += __shfl_xor(e1[i], m);
    }
  }
  float w0[2], w1[2];
#pragma unroll
  for (int i = 0; i < 2; i++) { w0[i] = __expf(e0[i]); w1[i] = __expf(e1[i]); }

  // pack: pk[row][col] = bf16(w*H), denom cols 128/129 = bf16(w), 130..143 = 0
#pragma unroll
  for (int i = 0; i < 2; i++) {
    const int row = ty + i*16;
#pragma unroll
    for (int jj = 0; jj < 8; jj++)
      pk[row][tx + jj*16] = f2bf((jj < 4 ? w0[i] : w1[i]) * acc[i][jj]);
    pk[row][128 + tx] = (tx == 0) ? f2bf(w0[i]) : (tx == 1) ? f2bf(w1[i]) : 0;
  }
  __syncthreads();

  // emit 576 uint4 words: word = n*64 + l
#pragma unroll
  for (int t = 0; t < 3; t++) {
    const int wid = t*256 + tid;
    if (wid < 576) {
      const int l = wid & 63, n = wid >> 6;
      const int col = n*16 + (l & 15), jb = (l >> 4) * 8;
      uint4 o;
      o.x = (unsigned)pk[jb+0][col] | ((unsigned)pk[jb+1][col] << 16);
      o.y = (unsigned)pk[jb+2][col] | ((unsigned)pk[jb+3][col] << 16);
      o.z = (unsigned)pk[jb+4][col] | ((unsigned)pk[jb+5][col] << 16);
      o.w = (unsigned)pk[jb+6][col] | ((unsigned)pk[jb+7][col] << 16);
      frag[((size_t)kb*NTILES + n)*64 + l] = o;
    }
  }
}

// ---------------------------------------------------------------- k_main
// accum[ks][8192][132] = adj[:, ks-slice] @ B[ks-slice, 144]  (bf16 MFMA, fp32 acc)
// 512-thread block (8 waves x 16-row strips), 128 rows x 1024 K per block.
// A (adj tile, 16 KB) AND B (frag tile, 9 KB) both staged via global_load_lds
// into a 4-deep LDS ring (100 KB total, 1 block/CU, 8 waves/CU), stage issued
// 2 steps ahead. B is loaded ONCE per block per step (was 8x redundant per-wave
// register loads -> ~14.5 TB/s cache demand; now ~1.9 TB/s). adj staged with
// NT cache policy (aux=2) so the 268 MB stream doesn't thrash L2 for B.
// Counted vmcnt per wave (4 for wave0 which also stages B-frag 8, 3 others) —
// never drains to 0 until the 2-step tail; raw s_barrier + sched_barrier(0).
// A rows XOR-swizzled via pre-swizzled global src (byte ^= (row&7)<<4).
__global__ __launch_bounds__(512, 2) void k_main(const int* __restrict__ adj,
                                                 const uint4* __restrict__ fragB,
                                                 float* __restrict__ accum) {
  const int mb = blockIdx.x >> 3;         // 0..63
  const int ks = blockIdx.x & 7;          // 0..7
  const int tid = threadIdx.x;
  const int wave = tid >> 6, lane = tid & 63;
  const int m16 = lane & 15, quad = lane >> 4;

  __shared__ int   tA[4][4096];           // 4 x 16 KB adj tiles (swizzled rows)
  __shared__ uint4 tB[4][576];            // 4 x 9 KB B tiles

  // A staging: wave w stages rows w*16 .. w*16+15 (chunks c = w*2, w*2+1).
  // lane l covers row c*8 + (l>>3), global 16B-slot ((l&7) ^ (l>>3)) of the
  // 128B row -> linear LDS write lands XOR-swizzled.
  const int lr = lane >> 3;
  const int lc = ((lane & 7) ^ lr) << 2;
  const int* gA = adj + (size_t)(mb*128)*N_NODES + ks*1024 + (size_t)lr*N_NODES + lc;

  // B staging: op t covers frag t (1 KB); wave w handles t=w, wave0 also t=8.
  const uint4* gB = fragB + (size_t)(ks*32)*576 + lane;

  auto stageA = [&](int slot, int kk) {
#pragma unroll
    for (int i = 0; i < 2; ++i) {
      const int c = wave*2 + i;
      const int* g = gA + (size_t)(c*8)*N_NODES + kk*32;
      __builtin_amdgcn_global_load_lds(
        (const __attribute__((address_space(1))) void*)g,
        (__attribute__((address_space(3))) void*)&tA[slot][c*256], 16, 0, 2 /*NT*/);
    }
  };
  auto stageB = [&](int slot, int kk) {
    const uint4* g = gB + (size_t)kk*576;
    __builtin_amdgcn_global_load_lds(
      (const __attribute__((address_space(1))) void*)(g + wave*64),
      (__attribute__((address_space(3))) void*)&tB[slot][wave*64], 16, 0, 0);
    if (wave == 0)
      __builtin_amdgcn_global_load_lds(
        (const __attribute__((address_space(1))) void*)(g + 8*64),
        (__attribute__((address_space(3))) void*)&tB[slot][8*64], 16, 0, 0);
  };

  // A read geometry: strip rows wave*16 + m16; swizzled byte offset.
  const int r0 = wave*16 + m16;
  const int swz = (r0 & 7) << 4;
  const int a0off = r0*128 + ((quad*32) ^ swz);

  f32x4 acc[NTILES];
#pragma unroll
  for (int n = 0; n < NTILES; n++) acc[n] = (f32x4){0.f, 0.f, 0.f, 0.f};

  auto conv8 = [&](i32x4 lo, i32x4 hi) -> bf16x8 {
    unsigned u0 = (lo[0] ? 0x3F80u : 0u) | (lo[1] ? 0x3F800000u : 0u);
    unsigned u1 = (lo[2] ? 0x3F80u : 0u) | (lo[3] ? 0x3F800000u : 0u);
    unsigned u2 = (hi[0] ? 0x3F80u : 0u) | (hi[1] ? 0x3F800000u : 0u);
    unsigned u3 = (hi[2] ? 0x3F80u : 0u) | (hi[3] ? 0x3F800000u : 0u);
    uu32x4 u = {u0, u1, u2, u3};
    return __builtin_bit_cast(bf16x8, u);
  };
  auto compute = [&](int slot) {
    const char* ta = (const char*)&tA[slot][0];
    i32x4 x0 = *(const i32x4*)(ta + a0off);
    i32x4 x1 = *(const i32x4*)(ta + (a0off ^ 16));
    bf16x8 af = conv8(x0, x1);
    const uu32x4* bp = (const uu32x4*)&tB[slot][0] + lane;
#pragma unroll
    for (int n = 0; n < NTILES; n++) {
      bf16x8 bfr = __builtin_bit_cast(bf16x8, bp[n*64]);
      acc[n] = __builtin_amdgcn_mfma_f32_16x16x32_bf16(af, bfr, acc[n], 0, 0, 0);
    }
  };

  // prologue: batches 0 and 1 in flight; retire batch 0, keep batch 1.
  stageA(0, 0); stageB(0, 0);
  stageA(1, 1); stageB(1, 1);
  if (wave == 0) asm volatile("s_waitcnt vmcnt(4)" ::: "memory");
  else           asm volatile("s_waitcnt vmcnt(3)" ::: "memory");
  __builtin_amdgcn_s_barrier();
  __builtin_amdgcn_sched_barrier(0);

  for (int kk = 0; kk < 32; ++kk) {
    if (kk + 2 < 32) { stageA((kk + 2) & 3, kk + 2); stageB((kk + 2) & 3, kk + 2); }
    compute(kk & 3);
    if (kk < 30) {
      // retire batch kk+1, keep batch kk+2 (wave0 issued 4 ops, others 3)
      if (wave == 0) asm volatile("s_waitcnt vmcnt(4)" ::: "memory");
      else           asm volatile("s_waitcnt vmcnt(3)" ::: "memory");
    } else {
      asm volatile("s_waitcnt vmcnt(0)" ::: "memory");  // tail drain (last 2 steps)
    }
    __builtin_amdgcn_s_barrier();
    __builtin_amdgcn_sched_barrier(0);
  }

  // epilogue: C/D layout col=lane&15, row=quad*4+reg. Plain stores.
  const int rb0 = mb*128 + wave*16 + quad*4;
  float* op = accum + (size_t)ks*N_NODES*ACC_STRIDE;
#pragma unroll
  for (int n = 0; n < NTILES; n++) {
    if (n == 8 && m16 >= HEADS) continue;  // cols 130..143 are padding
#pragma unroll
    for (int r = 0; r < 4; r++)
      op[(size_t)(rb0 + r)*ACC_STRIDE + n*16 + m16] = acc[n][r];
  }
}

// ---------------------------------------------------------------- k_div
// out[i][c] = (sum_ks num) / (sum_ks den); vectorized f32x4, 8 rows/block.
__global__ void k_div(const float* __restrict__ acc, float* __restrict__ out) {
  const int tid = threadIdx.x;
  const int r = tid >> 5, c4 = (tid & 31) << 2;   // 8 rows x 32 lanes x float4
  const int i = blockIdx.x * 8 + r;
  const int h = c4 >> 6;
  f32x4 num = (f32x4){0.f, 0.f, 0.f, 0.f};
  float den = 0.f;
#pragma unroll
  for (int s = 0; s < KSPLIT; s++) {
    const float* p = acc + ((size_t)s*N_NODES + i)*ACC_STRIDE;
    num += *(const f32x4*)(p + c4);
    den += p[FEAT + h];
  }
  f32x4 o = num / (f32x4){den, den, den, den};
  *(f32x4*)(out + (size_t)i*FEAT + c4) = o;
}

// ---------------------------------------------------------------- launch
extern "C" void kernel_launch(void* const* d_in, const int* in_sizes, int n_in,
                              void* d_out, int out_size, void* d_ws, size_t ws_size,
                              hipStream_t stream) {
  const float* x      = (const float*)d_in[0];
  const int*   adj    = (const int*)  d_in[1];
  const float* W      = (const float*)d_in[2];
  // d_in[3] = attn_l: cancels in softmax over j — unused.
  const float* attn_r = (const float*)d_in[4];

  char* ws = (char*)d_ws;
  uint4* frag = (uint4*)(ws + 0);              // 2.36 MB
  float* acc  = (float*)(ws + 4194304);        // 8 x 4.33 MB
  float* out  = (float*)d_out;

  hipLaunchKernelGGL(k_prep, dim3(256),  dim3(256), 0, stream, x, W, attn_r, frag);
  hipLaunchKernelGGL(k_main, dim3(512),  dim3(512), 0, stream, adj, frag, acc);
  hipLaunchKernelGGL(k_div,  dim3(1024), dim3(256), 0, stream, acc, out);
}